// Round 14
// baseline (106.700 us; speedup 1.0000x reference)
//
#include <hip/hip_runtime.h>

#define BAND 32
#define NITER (BAND + 4)
#define NSLOT 1024

__global__ __launch_bounds__(256) void nms_loss_kernel(
    const float* __restrict__ tl, const float* __restrict__ pl,
    double* __restrict__ acc_d, float* __restrict__ acc_f,
    int H, int W)
{
    const int y0  = blockIdx.x * BAND;
    const int ch  = blockIdx.y;
    const float* tc = tl + (size_t)ch * H * W;
    const float* pc = pl + (size_t)ch * H * W;
    const int tid  = threadIdx.x;
    const int lane = tid & 63;
    const int c0 = tid << 1;                    // this thread's 2 output columns
    const int oa = min(max(c0 - 2, 0), W - 2);  // clamped float2 bases
    const int oc = min(c0 + 2, W - 2);
    const bool xedge = (c0 == 0) || (c0 == W - 2);

    // register rings: P (5 rows), e (3 rows), t-center/mask (3 rows)
    float P1h[5][2], P2h[5][2], P3h[5][2];
    float eh[3][4], tch[3][2];
    // two pending-row slots (prefetch distance 2), statically selected by parity
    float tA[6], pA[6], tB[6], pB[6];

    // row(I): t row y0-2+I (clamp), p row y0-3+I (reflect)
    #define LOADROW(I, T6, P6) {                                                   \
        int tr_ = y0 - 2 + (I); tr_ = min(max(tr_, 0), H - 1);                      \
        int pr_ = y0 - 3 + (I); pr_ = pr_ < 0 ? -pr_ : (pr_ >= H ? 2*H-2-pr_ : pr_);\
        const float* tb_ = tc + (size_t)tr_ * W;                                    \
        const float* pb_ = pc + (size_t)pr_ * W;                                    \
        float2 a_ = *(const float2*)(tb_ + oa), b_ = *(const float2*)(tb_ + c0),    \
               c_ = *(const float2*)(tb_ + oc);                                     \
        T6[0]=a_.x; T6[1]=a_.y; T6[2]=b_.x; T6[3]=b_.y; T6[4]=c_.x; T6[5]=c_.y;     \
        a_ = *(const float2*)(pb_ + oa); b_ = *(const float2*)(pb_ + c0);           \
        c_ = *(const float2*)(pb_ + oc);                                            \
        P6[0]=a_.x; P6[1]=a_.y; P6[2]=b_.x; P6[3]=b_.y; P6[4]=c_.x; P6[5]=c_.y; }

    // consume pending row into P/e/mask rings (verified R12 arithmetic)
    #define CONSUME(T6, P6) {                                                       \
        if (!xedge) {                                                               \
            float s04 = T6[0] + T6[4], s13 = T6[1] + T6[3];                         \
            P1h[sP][0] = fmaf(-2.f, T6[2], s04);                                    \
            P3h[sP][0] = fmaf(6.f, T6[2], fmaf(4.f, s13, s04));                     \
            P2h[sP][0] = fmaf(2.f, T6[3] - T6[1], T6[4] - T6[0]);                   \
            float s04b = T6[1] + T6[5], s13b = T6[2] + T6[4];                       \
            P1h[sP][1] = fmaf(-2.f, T6[3], s04b);                                   \
            P3h[sP][1] = fmaf(6.f, T6[3], fmaf(4.f, s13b, s04b));                   \
            P2h[sP][1] = fmaf(2.f, T6[4] - T6[2], T6[5] - T6[1]);                   \
        } else if (c0 == 0) {                                                       \
            P1h[sP][0] = T6[4] - T6[3];                                             \
            P2h[sP][0] = fmaf(-2.f, T6[2], T6[3] + T6[4]);                          \
            P3h[sP][0] = fmaf(10.f, T6[2], fmaf(5.f, T6[3], T6[4]));                \
            P1h[sP][1] = fmaf(-2.f, T6[3], T6[2] + T6[5]);                          \
            P2h[sP][1] = fmaf(-3.f, T6[2], fmaf(2.f, T6[4], T6[5]));                \
            P3h[sP][1] = fmaf(5.f, T6[2], fmaf(6.f, T6[3], fmaf(4.f, T6[4], T6[5])));\
        } else {                                                                    \
            P1h[sP][0] = fmaf(-2.f, T6[2], T6[0] + T6[3]);                          \
            P2h[sP][0] = fmaf(3.f, T6[3], fmaf(-2.f, T6[1], -T6[0]));               \
            P3h[sP][0] = fmaf(5.f, T6[3], fmaf(6.f, T6[2], fmaf(4.f, T6[1], T6[0])));\
            P1h[sP][1] = T6[1] - T6[2];                                             \
            P2h[sP][1] = fmaf(2.f, T6[3], -T6[1] - T6[2]);                          \
            P3h[sP][1] = fmaf(10.f, T6[3], fmaf(5.f, T6[2], T6[1]));                \
        }                                                                           \
        tch[sE][0] = T6[2]; tch[sE][1] = T6[3];                                     \
        eh[sE][0] = __expf(0.1f * P6[1]);                                           \
        eh[sE][1] = __expf(0.1f * P6[2]);                                           \
        eh[sE][2] = __expf(0.1f * P6[3]);                                           \
        eh[sE][3] = __expf(0.1f * P6[4]); }

    LOADROW(0, tA, pA)
    LOADROW(1, tB, pB)

    float partial = 0.f;

    #pragma unroll
    for (int i = 0; i < NITER; ++i) {
        const int sP = i % 5, sE = i % 3;

        // ---- consume pending row i; immediately re-issue loads for row i+2
        if ((i & 1) == 0) {
            CONSUME(tA, pA)
            if (i + 2 < NITER) LOADROW(i + 2, tA, pA)
        } else {
            CONSUME(tB, pB)
            if (i + 2 < NITER) LOADROW(i + 2, tB, pB)
        }

        // ---- output row y = y0 + i - 4
        if (i >= 4) {
            const int y = y0 + i - 4;
            const int s0 = (i - 4) % 5, s1 = (i - 3) % 5, s2 = (i - 2) % 5,
                      s3 = (i - 1) % 5, s4 = i % 5;
            float xx[2], xy[2], yy[2];
            if (y >= 2 && y <= H - 3) {
                #pragma unroll
                for (int j = 0; j < 2; ++j) {
                    float a04 = P1h[s0][j] + P1h[s4][j], a13 = P1h[s1][j] + P1h[s3][j];
                    xx[j] = fmaf(6.f, P1h[s2][j], fmaf(4.f, a13, a04));      // wss
                    xy[j] = fmaf(2.f, P2h[s3][j] - P2h[s1][j], P2h[s4][j] - P2h[s0][j]); // wsd
                    yy[j] = fmaf(-2.f, P3h[s2][j], P3h[s0][j] + P3h[s4][j]); // wdd
                }
            } else {
                float wss[5], wsd[5], wdd[5];
                if (y == 0) {
                    wss[0]=0; wss[1]=0; wss[2]=10; wss[3]=5;  wss[4]=1;
                    wsd[0]=0; wsd[1]=0; wsd[2]=-4; wsd[3]=3;  wsd[4]=1;
                    wdd[0]=0; wdd[1]=0; wdd[2]=0;  wdd[3]=-1; wdd[4]=1;
                } else if (y == 1) {
                    wss[0]=0; wss[1]=5; wss[2]=6;  wss[3]=4;  wss[4]=1;
                    wsd[0]=0; wsd[1]=-3;wsd[2]=0;  wsd[3]=2;  wsd[4]=1;
                    wdd[0]=0; wdd[1]=1; wdd[2]=-2; wdd[3]=0;  wdd[4]=1;
                } else if (y == H - 1) {
                    wss[0]=1; wss[1]=5; wss[2]=10; wss[3]=0;  wss[4]=0;
                    wsd[0]=-1;wsd[1]=-3;wsd[2]=4;  wsd[3]=0;  wsd[4]=0;
                    wdd[0]=1; wdd[1]=-1;wdd[2]=0;  wdd[3]=0;  wdd[4]=0;
                } else { // y == H-2
                    wss[0]=1; wss[1]=4; wss[2]=6;  wss[3]=5;  wss[4]=0;
                    wsd[0]=-1;wsd[1]=-2;wsd[2]=0;  wsd[3]=3;  wsd[4]=0;
                    wdd[0]=1; wdd[1]=0; wdd[2]=-2; wdd[3]=1;  wdd[4]=0;
                }
                const int ss[5] = {s0, s1, s2, s3, s4};
                #pragma unroll
                for (int j = 0; j < 2; ++j) {
                    float X = 0.f, Y = 0.f, Z = 0.f;
                    #pragma unroll
                    for (int k = 0; k < 5; ++k) {
                        X = fmaf(wss[k], P1h[ss[k]][j], X);
                        Y = fmaf(wsd[k], P2h[ss[k]][j], Y);
                        Z = fmaf(wdd[k], P3h[ss[k]][j], Z);
                    }
                    xx[j] = X; xy[j] = Y; yy[j] = Z;
                }
            }

            const int et = (i - 2) % 3, em = (i - 1) % 3, eb = i % 3; // rows y-1, y, y+1
            #pragma unroll
            for (int j = 0; j < 2; ++j) {
                if (tch[et][j] > 0.f) {          // mask row y (ring slot (i-2)%3)
                    float den = xx[j] + 6.4e-6f;  // 64*(grad_xx+1e-7)
                    float sa  = 6.4e-6f - xy[j];  // 64*(1e-7-grad_xy)
                    float ax = fabsf(den), ay = fabsf(yy[j]);
                    bool isH = ay < 0.41421356f * ax;    // tan(22.5)
                    bool isV = ay >= 2.41421356f * ax;   // tan(67.5)
                    bool qp  = ((yy[j] * sa) * den) > 0.f;
                    float ec = eh[em][j + 1];
                    float n1 = isH ? eh[em][j + 2] : (isV ? eh[eb][j + 1] : (qp ? eh[eb][j] : eh[eb][j + 2]));
                    float n2 = isH ? eh[em][j]     : (isV ? eh[et][j + 1] : (qp ? eh[et][j + 2] : eh[et][j]));
                    partial += __logf(__fdividef(ec, ec + n1 + n2 + 1e-7f));
                }
            }
        }
    }

    // ---- wave reduction + spread atomics (no barriers anywhere) ----
    for (int off = 32; off > 0; off >>= 1)
        partial += __shfl_down(partial, off, 64);
    if (lane == 0) {
        int fid = (blockIdx.y * gridDim.x + blockIdx.x) * 4 + (tid >> 6);
        if (acc_d) atomicAdd(&acc_d[fid & (NSLOT - 1)], (double)partial);
        else       atomicAdd(acc_f, partial);
    }
}

__global__ void finalize_kernel(const double* acc_d, float* out,
                                int use_double, float inv_b)
{
    if (use_double) {
        int l = threadIdx.x;
        double s = 0.0;
        for (int i = l; i < NSLOT; i += 64) s += acc_d[i];
        for (int off = 32; off > 0; off >>= 1) s += __shfl_down(s, off, 64);
        if (l == 0) out[0] = (float)(-s * (double)inv_b);
    } else {
        if (threadIdx.x == 0) out[0] = -out[0] * inv_b;
    }
}

extern "C" void kernel_launch(void* const* d_in, const int* in_sizes, int n_in,
                              void* d_out, int out_size, void* d_ws, size_t ws_size,
                              hipStream_t stream)
{
    const float* tl = (const float*)d_in[0];
    const float* pl = (const float*)d_in[1];
    float* out = (float*)d_out;

    const int H = 512, W = 512, B = 4;

    double* acc_d = nullptr;
    float* acc_f = nullptr;
    int use_double = 0;
    if (ws_size >= NSLOT * sizeof(double)) {
        acc_d = (double*)d_ws;
        use_double = 1;
        hipMemsetAsync(acc_d, 0, NSLOT * sizeof(double), stream);
    } else {
        acc_f = out;
        hipMemsetAsync(out, 0, sizeof(float), stream);
    }

    dim3 grid(H / BAND, 76, 1);   // 16 bands x 76 channels = 1216 blocks, 512 cols/block
    nms_loss_kernel<<<grid, 256, 0, stream>>>(tl, pl, acc_d, acc_f, H, W);
    finalize_kernel<<<1, 64, 0, stream>>>(acc_d, out, use_double, 1.0f / (float)B);
}

// Round 15
// 59.947 us; speedup vs baseline: 1.7799x; 1.7799x over previous
//
#include <hip/hip_runtime.h>

#define BAND 16
#define NITER (BAND + 4)
#define NSLOT 1024

__global__ __launch_bounds__(64) void nms_loss_kernel(
    const float* __restrict__ tl, const float* __restrict__ pl,
    double* __restrict__ acc_d, float* __restrict__ acc_f,
    int H, int W)
{
    const int y0   = blockIdx.x * BAND;
    const int slab = blockIdx.y;               // 128-col slab
    const int ch   = blockIdx.z;
    const float* tc = tl + (size_t)ch * H * W;
    const float* pc = pl + (size_t)ch * H * W;
    const int tid  = threadIdx.x;              // 0..63, one wave per block
    const int c0 = (slab << 7) + (tid << 1);   // this thread's 2 output columns
    const int oa = min(max(c0 - 2, 0), W - 2); // clamped float2 bases
    const int oc = min(c0 + 2, W - 2);
    const bool xedge = (c0 == 0) || (c0 == W - 2);

    // register rings: P (5 rows), e (3 rows), t-center/mask (3 rows)
    float P1h[5][2], P2h[5][2], P3h[5][2];
    float eh[3][4], tch[3][2];
    // two pending-row slots (prefetch distance 2), statically selected by parity
    float tA[6], pA[6], tB[6], pB[6];

    // row(I): t row y0-2+I (clamp), p row y0-3+I (reflect)
    #define LOADROW(I, T6, P6) {                                                   \
        int tr_ = y0 - 2 + (I); tr_ = min(max(tr_, 0), H - 1);                      \
        int pr_ = y0 - 3 + (I); pr_ = pr_ < 0 ? -pr_ : (pr_ >= H ? 2*H-2-pr_ : pr_);\
        const float* tb_ = tc + (size_t)tr_ * W;                                    \
        const float* pb_ = pc + (size_t)pr_ * W;                                    \
        float2 a_ = *(const float2*)(tb_ + oa), b_ = *(const float2*)(tb_ + c0),    \
               c_ = *(const float2*)(tb_ + oc);                                     \
        T6[0]=a_.x; T6[1]=a_.y; T6[2]=b_.x; T6[3]=b_.y; T6[4]=c_.x; T6[5]=c_.y;     \
        a_ = *(const float2*)(pb_ + oa); b_ = *(const float2*)(pb_ + c0);           \
        c_ = *(const float2*)(pb_ + oc);                                            \
        P6[0]=a_.x; P6[1]=a_.y; P6[2]=b_.x; P6[3]=b_.y; P6[4]=c_.x; P6[5]=c_.y; }

    // consume pending row into P/e/mask rings (verified R12 arithmetic)
    #define CONSUME(T6, P6) {                                                       \
        if (!xedge) {                                                               \
            float s04 = T6[0] + T6[4], s13 = T6[1] + T6[3];                         \
            P1h[sP][0] = fmaf(-2.f, T6[2], s04);                                    \
            P3h[sP][0] = fmaf(6.f, T6[2], fmaf(4.f, s13, s04));                     \
            P2h[sP][0] = fmaf(2.f, T6[3] - T6[1], T6[4] - T6[0]);                   \
            float s04b = T6[1] + T6[5], s13b = T6[2] + T6[4];                       \
            P1h[sP][1] = fmaf(-2.f, T6[3], s04b);                                   \
            P3h[sP][1] = fmaf(6.f, T6[3], fmaf(4.f, s13b, s04b));                   \
            P2h[sP][1] = fmaf(2.f, T6[4] - T6[2], T6[5] - T6[1]);                   \
        } else if (c0 == 0) {                                                       \
            P1h[sP][0] = T6[4] - T6[3];                                             \
            P2h[sP][0] = fmaf(-2.f, T6[2], T6[3] + T6[4]);                          \
            P3h[sP][0] = fmaf(10.f, T6[2], fmaf(5.f, T6[3], T6[4]));                \
            P1h[sP][1] = fmaf(-2.f, T6[3], T6[2] + T6[5]);                          \
            P2h[sP][1] = fmaf(-3.f, T6[2], fmaf(2.f, T6[4], T6[5]));                \
            P3h[sP][1] = fmaf(5.f, T6[2], fmaf(6.f, T6[3], fmaf(4.f, T6[4], T6[5])));\
        } else {                                                                    \
            P1h[sP][0] = fmaf(-2.f, T6[2], T6[0] + T6[3]);                          \
            P2h[sP][0] = fmaf(3.f, T6[3], fmaf(-2.f, T6[1], -T6[0]));               \
            P3h[sP][0] = fmaf(5.f, T6[3], fmaf(6.f, T6[2], fmaf(4.f, T6[1], T6[0])));\
            P1h[sP][1] = T6[1] - T6[2];                                             \
            P2h[sP][1] = fmaf(2.f, T6[3], -T6[1] - T6[2]);                          \
            P3h[sP][1] = fmaf(10.f, T6[3], fmaf(5.f, T6[2], T6[1]));                \
        }                                                                           \
        tch[sE][0] = T6[2]; tch[sE][1] = T6[3];                                     \
        eh[sE][0] = __expf(0.1f * P6[1]);                                           \
        eh[sE][1] = __expf(0.1f * P6[2]);                                           \
        eh[sE][2] = __expf(0.1f * P6[3]);                                           \
        eh[sE][3] = __expf(0.1f * P6[4]); }

    LOADROW(0, tA, pA)
    LOADROW(1, tB, pB)

    float partial = 0.f;

    #pragma unroll
    for (int i = 0; i < NITER; ++i) {
        const int sP = i % 5, sE = i % 3;

        // ---- consume pending row i; immediately re-issue loads for row i+2
        if ((i & 1) == 0) {
            CONSUME(tA, pA)
            if (i + 2 < NITER) LOADROW(i + 2, tA, pA)
        } else {
            CONSUME(tB, pB)
            if (i + 2 < NITER) LOADROW(i + 2, tB, pB)
        }

        // ---- output row y = y0 + i - 4
        if (i >= 4) {
            const int y = y0 + i - 4;
            const int s0 = (i - 4) % 5, s1 = (i - 3) % 5, s2 = (i - 2) % 5,
                      s3 = (i - 1) % 5, s4 = i % 5;
            float xx[2], xy[2], yy[2];
            if (y >= 2 && y <= H - 3) {
                #pragma unroll
                for (int j = 0; j < 2; ++j) {
                    float a04 = P1h[s0][j] + P1h[s4][j], a13 = P1h[s1][j] + P1h[s3][j];
                    xx[j] = fmaf(6.f, P1h[s2][j], fmaf(4.f, a13, a04));      // wss
                    xy[j] = fmaf(2.f, P2h[s3][j] - P2h[s1][j], P2h[s4][j] - P2h[s0][j]); // wsd
                    yy[j] = fmaf(-2.f, P3h[s2][j], P3h[s0][j] + P3h[s4][j]); // wdd
                }
            } else {
                float wss[5], wsd[5], wdd[5];
                if (y == 0) {
                    wss[0]=0; wss[1]=0; wss[2]=10; wss[3]=5;  wss[4]=1;
                    wsd[0]=0; wsd[1]=0; wsd[2]=-4; wsd[3]=3;  wsd[4]=1;
                    wdd[0]=0; wdd[1]=0; wdd[2]=0;  wdd[3]=-1; wdd[4]=1;
                } else if (y == 1) {
                    wss[0]=0; wss[1]=5; wss[2]=6;  wss[3]=4;  wss[4]=1;
                    wsd[0]=0; wsd[1]=-3;wsd[2]=0;  wsd[3]=2;  wsd[4]=1;
                    wdd[0]=0; wdd[1]=1; wdd[2]=-2; wdd[3]=0;  wdd[4]=1;
                } else if (y == H - 1) {
                    wss[0]=1; wss[1]=5; wss[2]=10; wss[3]=0;  wss[4]=0;
                    wsd[0]=-1;wsd[1]=-3;wsd[2]=4;  wsd[3]=0;  wsd[4]=0;
                    wdd[0]=1; wdd[1]=-1;wdd[2]=0;  wdd[3]=0;  wdd[4]=0;
                } else { // y == H-2
                    wss[0]=1; wss[1]=4; wss[2]=6;  wss[3]=5;  wss[4]=0;
                    wsd[0]=-1;wsd[1]=-2;wsd[2]=0;  wsd[3]=3;  wsd[4]=0;
                    wdd[0]=1; wdd[1]=0; wdd[2]=-2; wdd[3]=1;  wdd[4]=0;
                }
                const int ss[5] = {s0, s1, s2, s3, s4};
                #pragma unroll
                for (int j = 0; j < 2; ++j) {
                    float X = 0.f, Y = 0.f, Z = 0.f;
                    #pragma unroll
                    for (int k = 0; k < 5; ++k) {
                        X = fmaf(wss[k], P1h[ss[k]][j], X);
                        Y = fmaf(wsd[k], P2h[ss[k]][j], Y);
                        Z = fmaf(wdd[k], P3h[ss[k]][j], Z);
                    }
                    xx[j] = X; xy[j] = Y; yy[j] = Z;
                }
            }

            const int et = (i - 2) % 3, em = (i - 1) % 3, eb = i % 3; // rows y-1, y, y+1
            #pragma unroll
            for (int j = 0; j < 2; ++j) {
                if (tch[et][j] > 0.f) {          // mask row y (ring slot (i-2)%3)
                    float den = xx[j] + 6.4e-6f;  // 64*(grad_xx+1e-7)
                    float sa  = 6.4e-6f - xy[j];  // 64*(1e-7-grad_xy)
                    float ax = fabsf(den), ay = fabsf(yy[j]);
                    bool isH = ay < 0.41421356f * ax;    // tan(22.5)
                    bool isV = ay >= 2.41421356f * ax;   // tan(67.5)
                    bool qp  = ((yy[j] * sa) * den) > 0.f;
                    float ec = eh[em][j + 1];
                    float n1 = isH ? eh[em][j + 2] : (isV ? eh[eb][j + 1] : (qp ? eh[eb][j] : eh[eb][j + 2]));
                    float n2 = isH ? eh[em][j]     : (isV ? eh[et][j + 1] : (qp ? eh[et][j + 2] : eh[et][j]));
                    partial += __logf(__fdividef(ec, ec + n1 + n2 + 1e-7f));
                }
            }
        }
    }

    // ---- wave reduction + spread atomics (single wave per block) ----
    for (int off = 32; off > 0; off >>= 1)
        partial += __shfl_down(partial, off, 64);
    if (tid == 0) {
        int fid = (blockIdx.z * gridDim.y + blockIdx.y) * gridDim.x + blockIdx.x;
        if (acc_d) atomicAdd(&acc_d[fid & (NSLOT - 1)], (double)partial);
        else       atomicAdd(acc_f, partial);
    }
}

__global__ void finalize_kernel(const double* acc_d, float* out,
                                int use_double, float inv_b)
{
    if (use_double) {
        int l = threadIdx.x;
        double s = 0.0;
        for (int i = l; i < NSLOT; i += 64) s += acc_d[i];
        for (int off = 32; off > 0; off >>= 1) s += __shfl_down(s, off, 64);
        if (l == 0) out[0] = (float)(-s * (double)inv_b);
    } else {
        if (threadIdx.x == 0) out[0] = -out[0] * inv_b;
    }
}

extern "C" void kernel_launch(void* const* d_in, const int* in_sizes, int n_in,
                              void* d_out, int out_size, void* d_ws, size_t ws_size,
                              hipStream_t stream)
{
    const float* tl = (const float*)d_in[0];
    const float* pl = (const float*)d_in[1];
    float* out = (float*)d_out;

    const int H = 512, W = 512, B = 4;

    double* acc_d = nullptr;
    float* acc_f = nullptr;
    int use_double = 0;
    if (ws_size >= NSLOT * sizeof(double)) {
        acc_d = (double*)d_ws;
        use_double = 1;
        hipMemsetAsync(acc_d, 0, NSLOT * sizeof(double), stream);
    } else {
        acc_f = out;
        hipMemsetAsync(out, 0, sizeof(float), stream);
    }

    // 32 bands x 4 slabs x 76 channels = 9728 single-wave blocks
    dim3 grid(H / BAND, W / 128, 76);
    nms_loss_kernel<<<grid, 64, 0, stream>>>(tl, pl, acc_d, acc_f, H, W);
    finalize_kernel<<<1, 64, 0, stream>>>(acc_d, out, use_double, 1.0f / (float)B);
}